// Round 10
// baseline (348.563 us; speedup 1.0000x reference)
//
#include <hip/hip_runtime.h>
#include <hip/hip_bf16.h>
#include <hip/hip_fp16.h>
#include <hip/hip_cooperative_groups.h>

namespace cg = cooperative_groups;

// GIN conv: out = MLP((1+eps)*x + segment_sum(x[src], dst))
// N_NODES=100000, N_EDGES=1600000, NFEAT=NHID=64, NCLASS=16, fp32.
//
// Round 15 = Round 14 resubmitted (acquisition timeout; unmeasured).
// R8 confirmed gather is request-bound (100->68.9us from request halving;
// FETCH const). Chain (5 kernels) ~117us of 185.5 => fuse the whole CSR
// build into ONE cooperative kernel (391 blocks x 512):
//   phase0 cvt+cursor-init | sync | phase1 part | sync |
//   phase2 scan (block 0)  | sync | phase3 per-bucket sort (SEPT 12)
// 6 launches -> 2; kills inter-kernel drains; if k_build > 68.8us it
// surfaces in top-5 (decomposes the chain cost). Gather kernel byte-for-
// byte identical to the R8-verified version (68.9us, absmax 0.0625).

#define NFEAT 64
#define NHID 64
#define NCLASS 16

#define PCAP 6144
#define MAXBUCK 512
#define BT 512
#define PEPT 8
#define SEPT2 12

// ---- fused CSR build (cooperative): cvt + init + part + scan + sort ----
__global__ __launch_bounds__(BT) void k_build(
    const float4* __restrict__ x4, uint2* __restrict__ xh,
    const int* __restrict__ ei,
    int* __restrict__ cursor, int* __restrict__ bbase,
    int* __restrict__ dsts, int* __restrict__ csr_src,
    int* __restrict__ row_ptr,
    int n_nodes, int n_edges, int nbuck, int n4)
{
    __shared__ int lcnt[MAXBUCK];   // phase1: bucket counts | phase3: cnt[256]
    __shared__ int sbase[MAXBUCK];  // phase1: scatter bases | phase3: off[256]
    __shared__ int sw[8];
    cg::grid_group grid = cg::this_grid();
    int tid = threadIdx.x;
    int bid = blockIdx.x;
    int lane = tid & 63, wid = tid >> 6;

    // ---- phase 0: x fp32 -> fp16, cursor init ----
    for (int i = bid * BT + tid; i < n4; i += gridDim.x * BT) {
        float4 v = x4[i];
        __half2 a = __floats2half2_rn(v.x, v.y);
        __half2 b = __floats2half2_rn(v.z, v.w);
        uint2 o;
        o.x = *reinterpret_cast<unsigned int*>(&a);
        o.y = *reinterpret_cast<unsigned int*>(&b);
        xh[i] = o;
    }
    if (bid == 0 && tid < nbuck) cursor[tid] = tid * PCAP;
    grid.sync();

    // ---- phase 1: partition edges into buckets (block = 4096-edge slice) ----
    {
        for (int i = tid; i < nbuck; i += BT) lcnt[i] = 0;
        __syncthreads();
        int e0 = bid * (BT * PEPT);
        int bk[PEPT], rk[PEPT], pk[PEPT];
        #pragma unroll
        for (int k = 0; k < PEPT; ++k) {
            int e = e0 + k * BT + tid;
            if (e < n_edges) {
                int src = ei[e];
                int dst = ei[n_edges + e];
                int b = dst >> 8;
                bk[k] = b;
                pk[k] = (src << 8) | (dst & 255);
                rk[k] = atomicAdd(&lcnt[b], 1);
            } else bk[k] = -1;
        }
        __syncthreads();
        for (int i = tid; i < nbuck; i += BT)
            sbase[i] = lcnt[i] ? atomicAdd(&cursor[i], lcnt[i]) : 0;
        __syncthreads();
        #pragma unroll
        for (int k = 0; k < PEPT; ++k)
            if (bk[k] >= 0) dsts[sbase[bk[k]] + rk[k]] = pk[k];
    }
    grid.sync();

    // ---- phase 2: scan bucket sizes -> bucket bases (block 0 only) ----
    if (bid == 0) {
        int v = (tid < nbuck) ? (cursor[tid] - tid * PCAP) : 0;
        int s = v;
        #pragma unroll
        for (int off = 1; off < 64; off <<= 1) {
            int u = __shfl_up(s, off);
            if (lane >= off) s += u;
        }
        if (lane == 63) sw[wid] = s;
        __syncthreads();
        if (tid == 0) { int a = 0; for (int i = 0; i < 8; ++i) { int tmp = sw[i]; sw[i] = a; a += tmp; } }
        __syncthreads();
        if (tid < nbuck) bbase[tid] = (s - v) + sw[wid];
        if (tid == 0) row_ptr[n_nodes] = n_edges;
    }
    grid.sync();

    // ---- phase 3: per-bucket counting sort (block = bucket) ----
    {
        int b = bid;
        int s = cursor[b] - b * PCAP;
        int gin = b * PCAP;
        if (tid < 256) lcnt[tid] = 0;
        __syncthreads();

        int dk[SEPT2], rk[SEPT2], sk[SEPT2];
        #pragma unroll
        for (int k = 0; k < SEPT2; ++k) {
            int i = k * BT + tid;
            if (i < s) {
                int p = dsts[gin + i];
                int d = p & 255;
                dk[k] = d;
                sk[k] = p >> 8;
                rk[k] = atomicAdd(&lcnt[d], 1);
            } else dk[k] = -1;
        }
        __syncthreads();
        if (wid == 0) {
            int c0 = lcnt[lane * 4], c1 = lcnt[lane * 4 + 1], c2 = lcnt[lane * 4 + 2], c3 = lcnt[lane * 4 + 3];
            int p1 = c0, p2 = p1 + c1, p3 = p2 + c2, p4 = p3 + c3;
            int ss = p4;
            #pragma unroll
            for (int o = 1; o < 64; o <<= 1) {
                int u = __shfl_up(ss, o);
                if (lane >= o) ss += u;
            }
            int base = ss - p4;
            sbase[lane * 4] = base; sbase[lane * 4 + 1] = base + p1;
            sbase[lane * 4 + 2] = base + p2; sbase[lane * 4 + 3] = base + p3;
        }
        __syncthreads();
        int bb = bbase[b];
        #pragma unroll
        for (int k = 0; k < SEPT2; ++k)
            if (dk[k] >= 0) csr_src[bb + sbase[dk[k]] + rk[k]] = sk[k];
        int node = b * 256 + tid;
        if (tid < 256 && node < n_nodes) row_ptr[node] = bb + sbase[tid];
    }
}

// ---- k4: fused gather + MLP, 4 nodes/wave, 16B fp16 loads, 2 edges in flight ----
// (byte-identical to the R8-verified kernel: 68.9us, FETCH 92MB)
__global__ __launch_bounds__(512) void k_gather_mlp(
    const float4* __restrict__ x4,     // [n][16] fp32 (self term)
    const uint2* __restrict__ xh,      // [n][16] fp16x4 (neighbor gather)
    const int* __restrict__ row_ptr,
    const int* __restrict__ csr_src,
    const float* __restrict__ eps_p,
    const float* __restrict__ W1,
    const float* __restrict__ b1,
    const float* __restrict__ W2,
    const float* __restrict__ b2,
    float* __restrict__ out,
    int n_nodes)
{
    __shared__ float sW1[NFEAT * NHID];   // [k][j] 16 KB
    __shared__ float sW2[NHID * 17];      // [j][c] padded
    __shared__ float sb1[NHID];
    __shared__ float sb2[NCLASS];
    __shared__ float sh0[32][68];         // 32 nodes/block, padded rows
    __shared__ float sh1[32][68];
    __shared__ int   sIdx[8][64];

    int tid = threadIdx.x;
    for (int i = tid; i < NFEAT * NHID; i += 512) sW1[i] = W1[i];
    for (int i = tid; i < NHID * NCLASS; i += 512) sW2[(i >> 4) * 17 + (i & 15)] = W2[i];
    if (tid < NHID) sb1[tid] = b1[tid];
    if (tid < NCLASS) sb2[tid] = b2[tid];
    __syncthreads();

    float eps1 = 1.0f + eps_p[0];
    int wave = tid >> 6;
    int lane = tid & 63;
    int q = lane >> 4;        // node sub-index 0..3
    int f = lane & 15;        // staging slot 0..15 / layer2 class slot
    int s8 = (lane >> 3) & 1; // edge parity within group
    int f8 = lane & 7;        // feature octet 0..7 (16B of fp16)
    int nloc = wave * 4 + q;  // local node row

    for (int nb0 = blockIdx.x * 32; nb0 < n_nodes; nb0 += gridDim.x * 32) {
        int myNode = nb0 + nloc;
        bool valid = myNode < n_nodes;
        int s = 0, e = 0;
        if (valid) { s = row_ptr[myNode]; e = row_ptr[myNode + 1]; }
        int dmax = e - s;
        dmax = max(dmax, __shfl_xor(dmax, 16));
        dmax = max(dmax, __shfl_xor(dmax, 32));

        // accA = features f8*8..+3, accB = f8*8+4..+7 (partial over edge parity s8)
        float4 accA = make_float4(0.f, 0.f, 0.f, 0.f);
        float4 accB = make_float4(0.f, 0.f, 0.f, 0.f);
        for (int base = 0; base < dmax; base += 16) {
            int p = s + base + f;                       // lane stages slot q*16+f
            sIdx[wave][lane] = (p < e) ? csr_src[p] : -1;
            // wave-lockstep LDS write->read, no barrier
            #pragma unroll
            for (int t = 0; t < 8; ++t) {
                int idx = sIdx[wave][q * 16 + t * 2 + s8];
                if (idx >= 0) {
                    const uint4* rp = (const uint4*)(xh + (size_t)idx * 16);
                    uint4 u = rp[f8];                   // 16B = 8 fp16 features
                    __half2 h0 = *reinterpret_cast<__half2*>(&u.x);
                    __half2 h1 = *reinterpret_cast<__half2*>(&u.y);
                    __half2 h2 = *reinterpret_cast<__half2*>(&u.z);
                    __half2 h3 = *reinterpret_cast<__half2*>(&u.w);
                    float2 g0 = __half22float2(h0);
                    float2 g1 = __half22float2(h1);
                    float2 g2 = __half22float2(h2);
                    float2 g3 = __half22float2(h3);
                    accA.x += g0.x; accA.y += g0.y; accA.z += g1.x; accA.w += g1.y;
                    accB.x += g2.x; accB.y += g2.y; accB.z += g3.x; accB.w += g3.y;
                }
            }
        }
        // combine the two edge-parity partials (lane ^ 8 within 16-lane group)
        accA.x += __shfl_xor(accA.x, 8); accA.y += __shfl_xor(accA.y, 8);
        accA.z += __shfl_xor(accA.z, 8); accA.w += __shfl_xor(accA.w, 8);
        accB.x += __shfl_xor(accB.x, 8); accB.y += __shfl_xor(accB.y, 8);
        accB.z += __shfl_xor(accB.z, 8); accB.w += __shfl_xor(accB.w, 8);
        if (s8 == 0) {
            if (valid) {
                float4 xa = x4[(size_t)myNode * 16 + f8 * 2];
                float4 xb = x4[(size_t)myNode * 16 + f8 * 2 + 1];
                accA.x += eps1 * xa.x; accA.y += eps1 * xa.y;
                accA.z += eps1 * xa.z; accA.w += eps1 * xa.w;
                accB.x += eps1 * xb.x; accB.y += eps1 * xb.y;
                accB.z += eps1 * xb.z; accB.w += eps1 * xb.w;
            }
            *(float4*)&sh0[nloc][f8 * 8] = accA;
            *(float4*)&sh0[nloc][f8 * 8 + 4] = accB;
        }

        // layer1: lane j computes h1[j] for the wave's 4 nodes
        int r = wave * 4;
        float a0 = sb1[lane], a1 = a0, a2 = a0, a3 = a0;
        #pragma unroll
        for (int kk = 0; kk < 16; ++kk) {
            float4 h0 = *(const float4*)&sh0[r + 0][kk * 4];   // broadcast reads
            float4 h1v = *(const float4*)&sh0[r + 1][kk * 4];
            float4 h2 = *(const float4*)&sh0[r + 2][kk * 4];
            float4 h3 = *(const float4*)&sh0[r + 3][kk * 4];
            #pragma unroll
            for (int i = 0; i < 4; ++i) {
                float w = sW1[(kk * 4 + i) * NHID + lane];
                a0 += ((const float*)&h0)[i] * w;
                a1 += ((const float*)&h1v)[i] * w;
                a2 += ((const float*)&h2)[i] * w;
                a3 += ((const float*)&h3)[i] * w;
            }
        }
        sh1[r + 0][lane] = fmaxf(a0, 0.f);
        sh1[r + 1][lane] = fmaxf(a1, 0.f);
        sh1[r + 2][lane] = fmaxf(a2, 0.f);
        sh1[r + 3][lane] = fmaxf(a3, 0.f);

        // layer2: lane (q,f) -> out[myNode][f]
        float o = sb2[f];
        #pragma unroll
        for (int jj = 0; jj < 16; ++jj) {
            float4 hv = *(const float4*)&sh1[nloc][jj * 4];
            o += hv.x * sW2[(jj * 4 + 0) * 17 + f];
            o += hv.y * sW2[(jj * 4 + 1) * 17 + f];
            o += hv.z * sW2[(jj * 4 + 2) * 17 + f];
            o += hv.w * sW2[(jj * 4 + 3) * 17 + f];
        }
        if (valid) out[(size_t)myNode * NCLASS + f] = o;
    }
}

extern "C" void kernel_launch(void* const* d_in, const int* in_sizes, int n_in,
                              void* d_out, int out_size, void* d_ws, size_t ws_size,
                              hipStream_t stream) {
    const float* x   = (const float*)d_in[0];
    const int*   ei  = (const int*)d_in[1];
    const float* eps = (const float*)d_in[2];
    const float* W1  = (const float*)d_in[3];
    const float* b1  = (const float*)d_in[4];
    const float* W2  = (const float*)d_in[5];
    const float* b2  = (const float*)d_in[6];
    float* out = (float*)d_out;

    int n_nodes = in_sizes[0] / NFEAT;            // 100000
    int n_edges = in_sizes[1] / 2;                // 1600000
    int nbuck = (n_nodes + 255) / 256;            // 391

    char* ws = (char*)d_ws;
    int* cursor  = (int*)ws;
    int* bbase   = (int*)(ws + 2048);
    int* dsts    = (int*)(ws + 4096);
    size_t o_rp  = 4096 + (size_t)nbuck * PCAP * 4;        // dsts end
    int* row_ptr = (int*)(ws + o_rp);
    int* csr_src = (int*)(ws + o_rp + 400128);
    size_t o_xh  = o_rp + 400128 + (size_t)n_edges * 4;    // csr end
    o_xh = (o_xh + 15) & ~(size_t)15;
    uint2* xh    = (uint2*)(ws + o_xh);                    // [n][16] fp16x4, 12.8MB

    int n4 = n_nodes * 16;

    const float4* x4c = (const float4*)x;
    uint2* xhp = xh;
    const int* eip = ei;
    int* cursorp = cursor; int* bbasep = bbase; int* dstsp = dsts;
    int* csrp = csr_src; int* rpp = row_ptr;
    void* bargs[] = { &x4c, &xhp, &eip, &cursorp, &bbasep, &dstsp, &csrp, &rpp,
                      &n_nodes, &n_edges, &nbuck, &n4 };
    hipLaunchCooperativeKernel((void*)k_build, dim3(nbuck), dim3(BT),
                               bargs, 0, stream);

    int ntile = (n_nodes + 31) / 32;
    int ngrid = ntile < 1024 ? ntile : 1024;      // grid-stride ~3 tiles/block
    k_gather_mlp<<<ngrid, 512, 0, stream>>>(
        (const float4*)x, xh, row_ptr, csr_src, eps, W1, b1, W2, b2, out, n_nodes);
}

// Round 11
// 183.552 us; speedup vs baseline: 1.8990x; 1.8990x over previous
//
#include <hip/hip_runtime.h>
#include <hip/hip_bf16.h>
#include <hip/hip_fp16.h>

// GIN conv: out = MLP((1+eps)*x + segment_sum(x[src], dst))
// N_NODES=100000, N_EDGES=1600000, NFEAT=NHID=64, NCLASS=16, fp32.
//
// Round 16: cooperative fusion (R14) REGRESSED 185.5->348.6us (k_build
// 193us: grid sized for buckets starved the cvt phase; 3 grid.syncs
// serialized; coop+graph profiling pathology). REVERT to R8-verified
// kernels + one change: kill the scan dependency.
//   - csr_src at FIXED per-bucket bases (b*PCAP; inter-bucket gaps OK)
//   - k_bsort writes row_start[]/row_end[] per node (no compact row_ptr)
//   - k_bscan deleted; k_init merged into k_cvt.  Chain: 6 -> 4 launches,
//     no 1-block kernel with device-wide drains.
// Gather kernel = R8 (68.9us, FETCH 92MB) except row_start/row_end reads.

#define NFEAT 64
#define NHID 64
#define NCLASS 16

#define PCAP 6144
#define MAXBUCK 512
#define PT 512
#define PEPT 8
#define ST 1024
#define SEPT 6

// ---- k0: x fp32 -> fp16 + cursor init (merged) ----
__global__ __launch_bounds__(512) void k_cvt(
    const float4* __restrict__ x4, uint2* __restrict__ xh,
    int* __restrict__ cursor, int n4, int nbuck)
{
    int i = blockIdx.x * 512 + threadIdx.x;
    if (i < n4) {
        float4 v = x4[i];
        __half2 a = __floats2half2_rn(v.x, v.y);
        __half2 b = __floats2half2_rn(v.z, v.w);
        uint2 o;
        o.x = *reinterpret_cast<unsigned int*>(&a);
        o.y = *reinterpret_cast<unsigned int*>(&b);
        xh[i] = o;
    }
    if (blockIdx.x == 0 && threadIdx.x < nbuck)
        cursor[threadIdx.x] = threadIdx.x * PCAP;
}

// ---- k1: partition edges into buckets by dst>>8, packed (src<<8)|(dst&255) ----
__global__ __launch_bounds__(PT) void k_part(
    const int* __restrict__ ei, int* __restrict__ cursor,
    int* __restrict__ dsts, int n_edges, int nbuck)
{
    __shared__ int lcnt[MAXBUCK];
    __shared__ int sbase[MAXBUCK];
    int tid = threadIdx.x;
    for (int i = tid; i < nbuck; i += PT) lcnt[i] = 0;
    __syncthreads();

    int e0 = blockIdx.x * (PT * PEPT);
    int bk[PEPT], rk[PEPT], pk[PEPT];
    #pragma unroll
    for (int k = 0; k < PEPT; ++k) {
        int e = e0 + k * PT + tid;
        if (e < n_edges) {
            int src = ei[e];
            int dst = ei[n_edges + e];
            int b = dst >> 8;
            bk[k] = b;
            pk[k] = (src << 8) | (dst & 255);
            rk[k] = atomicAdd(&lcnt[b], 1);
        } else bk[k] = -1;
    }
    __syncthreads();
    for (int i = tid; i < nbuck; i += PT)
        sbase[i] = lcnt[i] ? atomicAdd(&cursor[i], lcnt[i]) : 0;
    __syncthreads();
    #pragma unroll
    for (int k = 0; k < PEPT; ++k)
        if (bk[k] >= 0) dsts[sbase[bk[k]] + rk[k]] = pk[k];
}

// ---- k3: per-bucket counting sort -> csr_src at fixed base + row_start/end ----
__global__ __launch_bounds__(ST) void k_bsort(
    const int* __restrict__ dsts, const int* __restrict__ cursor,
    int* __restrict__ csr_src,
    int* __restrict__ row_start, int* __restrict__ row_end, int n_nodes)
{
    __shared__ int cnt[256];
    __shared__ int off[256];
    int b = blockIdx.x;
    int tid = threadIdx.x, lane = tid & 63, wid = tid >> 6;
    int s = cursor[b] - b * PCAP;
    int gin = b * PCAP;
    if (tid < 256) cnt[tid] = 0;
    __syncthreads();

    int dk[SEPT], rk[SEPT], sk[SEPT];
    #pragma unroll
    for (int k = 0; k < SEPT; ++k) {
        int i = k * ST + tid;
        if (i < s) {
            int p = dsts[gin + i];
            int d = p & 255;
            dk[k] = d;
            sk[k] = p >> 8;
            rk[k] = atomicAdd(&cnt[d], 1);
        } else dk[k] = -1;
    }
    __syncthreads();
    if (wid == 0) {
        int c0 = cnt[lane * 4], c1 = cnt[lane * 4 + 1], c2 = cnt[lane * 4 + 2], c3 = cnt[lane * 4 + 3];
        int p1 = c0, p2 = p1 + c1, p3 = p2 + c2, p4 = p3 + c3;
        int ss = p4;
        #pragma unroll
        for (int o = 1; o < 64; o <<= 1) {
            int u = __shfl_up(ss, o);
            if (lane >= o) ss += u;
        }
        int base = ss - p4;
        off[lane * 4] = base; off[lane * 4 + 1] = base + p1;
        off[lane * 4 + 2] = base + p2; off[lane * 4 + 3] = base + p3;
    }
    __syncthreads();
    int bb = b * PCAP;                      // FIXED base — no scan needed
    #pragma unroll
    for (int k = 0; k < SEPT; ++k)
        if (dk[k] >= 0) csr_src[bb + off[dk[k]] + rk[k]] = sk[k];
    int node = b * 256 + tid;
    if (tid < 256 && node < n_nodes) {
        row_start[node] = bb + off[tid];
        row_end[node]   = bb + off[tid] + cnt[tid];
    }
}

// ---- k4: fused gather + MLP, 4 nodes/wave, 16B fp16 loads, 2 edges in flight ----
// (R8-verified structure; only row_start/row_end reads differ)
__global__ __launch_bounds__(512) void k_gather_mlp(
    const float4* __restrict__ x4,     // [n][16] fp32 (self term)
    const uint2* __restrict__ xh,      // [n][16] fp16x4 (neighbor gather)
    const int* __restrict__ row_start,
    const int* __restrict__ row_end,
    const int* __restrict__ csr_src,
    const float* __restrict__ eps_p,
    const float* __restrict__ W1,
    const float* __restrict__ b1,
    const float* __restrict__ W2,
    const float* __restrict__ b2,
    float* __restrict__ out,
    int n_nodes)
{
    __shared__ float sW1[NFEAT * NHID];   // [k][j] 16 KB
    __shared__ float sW2[NHID * 17];      // [j][c] padded
    __shared__ float sb1[NHID];
    __shared__ float sb2[NCLASS];
    __shared__ float sh0[32][68];         // 32 nodes/block, padded rows
    __shared__ float sh1[32][68];
    __shared__ int   sIdx[8][64];

    int tid = threadIdx.x;
    for (int i = tid; i < NFEAT * NHID; i += 512) sW1[i] = W1[i];
    for (int i = tid; i < NHID * NCLASS; i += 512) sW2[(i >> 4) * 17 + (i & 15)] = W2[i];
    if (tid < NHID) sb1[tid] = b1[tid];
    if (tid < NCLASS) sb2[tid] = b2[tid];
    __syncthreads();

    float eps1 = 1.0f + eps_p[0];
    int wave = tid >> 6;
    int lane = tid & 63;
    int q = lane >> 4;        // node sub-index 0..3
    int f = lane & 15;        // staging slot 0..15 / layer2 class slot
    int s8 = (lane >> 3) & 1; // edge parity within group
    int f8 = lane & 7;        // feature octet 0..7 (16B of fp16)
    int nloc = wave * 4 + q;  // local node row

    for (int nb0 = blockIdx.x * 32; nb0 < n_nodes; nb0 += gridDim.x * 32) {
        int myNode = nb0 + nloc;
        bool valid = myNode < n_nodes;
        int s = 0, e = 0;
        if (valid) { s = row_start[myNode]; e = row_end[myNode]; }
        int dmax = e - s;
        dmax = max(dmax, __shfl_xor(dmax, 16));
        dmax = max(dmax, __shfl_xor(dmax, 32));

        // accA = features f8*8..+3, accB = f8*8+4..+7 (partial over edge parity s8)
        float4 accA = make_float4(0.f, 0.f, 0.f, 0.f);
        float4 accB = make_float4(0.f, 0.f, 0.f, 0.f);
        for (int base = 0; base < dmax; base += 16) {
            int p = s + base + f;                       // lane stages slot q*16+f
            sIdx[wave][lane] = (p < e) ? csr_src[p] : -1;
            // wave-lockstep LDS write->read, no barrier
            #pragma unroll
            for (int t = 0; t < 8; ++t) {
                int idx = sIdx[wave][q * 16 + t * 2 + s8];
                if (idx >= 0) {
                    const uint4* rp = (const uint4*)(xh + (size_t)idx * 16);
                    uint4 u = rp[f8];                   // 16B = 8 fp16 features
                    __half2 h0 = *reinterpret_cast<__half2*>(&u.x);
                    __half2 h1 = *reinterpret_cast<__half2*>(&u.y);
                    __half2 h2 = *reinterpret_cast<__half2*>(&u.z);
                    __half2 h3 = *reinterpret_cast<__half2*>(&u.w);
                    float2 g0 = __half22float2(h0);
                    float2 g1 = __half22float2(h1);
                    float2 g2 = __half22float2(h2);
                    float2 g3 = __half22float2(h3);
                    accA.x += g0.x; accA.y += g0.y; accA.z += g1.x; accA.w += g1.y;
                    accB.x += g2.x; accB.y += g2.y; accB.z += g3.x; accB.w += g3.y;
                }
            }
        }
        // combine the two edge-parity partials (lane ^ 8 within 16-lane group)
        accA.x += __shfl_xor(accA.x, 8); accA.y += __shfl_xor(accA.y, 8);
        accA.z += __shfl_xor(accA.z, 8); accA.w += __shfl_xor(accA.w, 8);
        accB.x += __shfl_xor(accB.x, 8); accB.y += __shfl_xor(accB.y, 8);
        accB.z += __shfl_xor(accB.z, 8); accB.w += __shfl_xor(accB.w, 8);
        if (s8 == 0) {
            if (valid) {
                float4 xa = x4[(size_t)myNode * 16 + f8 * 2];
                float4 xb = x4[(size_t)myNode * 16 + f8 * 2 + 1];
                accA.x += eps1 * xa.x; accA.y += eps1 * xa.y;
                accA.z += eps1 * xa.z; accA.w += eps1 * xa.w;
                accB.x += eps1 * xb.x; accB.y += eps1 * xb.y;
                accB.z += eps1 * xb.z; accB.w += eps1 * xb.w;
            }
            *(float4*)&sh0[nloc][f8 * 8] = accA;
            *(float4*)&sh0[nloc][f8 * 8 + 4] = accB;
        }

        // layer1: lane j computes h1[j] for the wave's 4 nodes
        int r = wave * 4;
        float a0 = sb1[lane], a1 = a0, a2 = a0, a3 = a0;
        #pragma unroll
        for (int kk = 0; kk < 16; ++kk) {
            float4 h0 = *(const float4*)&sh0[r + 0][kk * 4];   // broadcast reads
            float4 h1v = *(const float4*)&sh0[r + 1][kk * 4];
            float4 h2 = *(const float4*)&sh0[r + 2][kk * 4];
            float4 h3 = *(const float4*)&sh0[r + 3][kk * 4];
            #pragma unroll
            for (int i = 0; i < 4; ++i) {
                float w = sW1[(kk * 4 + i) * NHID + lane];
                a0 += ((const float*)&h0)[i] * w;
                a1 += ((const float*)&h1v)[i] * w;
                a2 += ((const float*)&h2)[i] * w;
                a3 += ((const float*)&h3)[i] * w;
            }
        }
        sh1[r + 0][lane] = fmaxf(a0, 0.f);
        sh1[r + 1][lane] = fmaxf(a1, 0.f);
        sh1[r + 2][lane] = fmaxf(a2, 0.f);
        sh1[r + 3][lane] = fmaxf(a3, 0.f);

        // layer2: lane (q,f) -> out[myNode][f]
        float o = sb2[f];
        #pragma unroll
        for (int jj = 0; jj < 16; ++jj) {
            float4 hv = *(const float4*)&sh1[nloc][jj * 4];
            o += hv.x * sW2[(jj * 4 + 0) * 17 + f];
            o += hv.y * sW2[(jj * 4 + 1) * 17 + f];
            o += hv.z * sW2[(jj * 4 + 2) * 17 + f];
            o += hv.w * sW2[(jj * 4 + 3) * 17 + f];
        }
        if (valid) out[(size_t)myNode * NCLASS + f] = o;
    }
}

extern "C" void kernel_launch(void* const* d_in, const int* in_sizes, int n_in,
                              void* d_out, int out_size, void* d_ws, size_t ws_size,
                              hipStream_t stream) {
    const float* x   = (const float*)d_in[0];
    const int*   ei  = (const int*)d_in[1];
    const float* eps = (const float*)d_in[2];
    const float* W1  = (const float*)d_in[3];
    const float* b1  = (const float*)d_in[4];
    const float* W2  = (const float*)d_in[5];
    const float* b2  = (const float*)d_in[6];
    float* out = (float*)d_out;

    int n_nodes = in_sizes[0] / NFEAT;            // 100000
    int n_edges = in_sizes[1] / 2;                // 1600000
    int nbuck = (n_nodes + 255) / 256;            // 391

    char* ws = (char*)d_ws;
    int* cursor    = (int*)ws;                               // 2KB
    int* dsts      = (int*)(ws + 4096);                      // nbuck*PCAP*4
    size_t o_rs    = 4096 + (size_t)nbuck * PCAP * 4;
    int* row_start = (int*)(ws + o_rs);                      // 400128
    int* row_end   = (int*)(ws + o_rs + 400128);             // 400128
    int* csr_src   = (int*)(ws + o_rs + 800256);             // nbuck*PCAP*4
    size_t o_xh    = o_rs + 800256 + (size_t)nbuck * PCAP * 4;
    o_xh = (o_xh + 15) & ~(size_t)15;
    uint2* xh      = (uint2*)(ws + o_xh);                    // [n][16] fp16x4

    int n4 = n_nodes * 16;
    k_cvt<<<(n4 + 511) / 512, 512, 0, stream>>>((const float4*)x, xh, cursor, n4, nbuck);
    k_part<<<(n_edges + PT * PEPT - 1) / (PT * PEPT), PT, 0, stream>>>(
        ei, cursor, dsts, n_edges, nbuck);
    k_bsort<<<nbuck, ST, 0, stream>>>(dsts, cursor, csr_src, row_start, row_end, n_nodes);
    int ntile = (n_nodes + 31) / 32;
    int ngrid = ntile < 1024 ? ntile : 1024;      // grid-stride ~3 tiles/block
    k_gather_mlp<<<ngrid, 512, 0, stream>>>(
        (const float4*)x, xh, row_start, row_end, csr_src, eps, W1, b1, W2, b2, out, n_nodes);
}

// Round 13
// 173.671 us; speedup vs baseline: 2.0070x; 1.0569x over previous
//
#include <hip/hip_runtime.h>
#include <hip/hip_bf16.h>
#include <hip/hip_fp16.h>

// GIN conv: out = MLP((1+eps)*x + segment_sum(x[src], dst))
// N_NODES=100000, N_EDGES=1600000, NFEAT=NHID=64, NCLASS=16, fp32.
//
// Round 18 = Round 17 resubmitted (acquisition timeout; unmeasured).
// R11 measured: launch-count reduction bought ~2us => chain cost (~114us)
// is INSIDE k_part/k_bsort. R10 fused counters: WRITE_SIZE ~2x ideal =>
// random 4B scatter writes amplify. This round: LDS-compaction scatter.
//  - k_part: count -> 512-wide block scan -> compact (val,bid) in LDS ->
//    linear write-out (per-bucket runs instead of random 4B singles).
//  - k_bsort: scatter src into lval[off+rk] in LDS -> csr window written
//    FULLY SEQUENTIALLY (contiguous [bb, bb+s)).
// Everything else byte-identical to R11 (183.55us, gather 69us verified).

#define NFEAT 64
#define NHID 64
#define NCLASS 16

#define PCAP 6144
#define PT 512
#define PEPT 8
#define ST 1024
#define SEPT 6

// ---- k0: x fp32 -> fp16 + cursor init (merged) ----
__global__ __launch_bounds__(512) void k_cvt(
    const float4* __restrict__ x4, uint2* __restrict__ xh,
    int* __restrict__ cursor, int n4, int nbuck)
{
    int i = blockIdx.x * 512 + threadIdx.x;
    if (i < n4) {
        float4 v = x4[i];
        __half2 a = __floats2half2_rn(v.x, v.y);
        __half2 b = __floats2half2_rn(v.z, v.w);
        uint2 o;
        o.x = *reinterpret_cast<unsigned int*>(&a);
        o.y = *reinterpret_cast<unsigned int*>(&b);
        xh[i] = o;
    }
    if (blockIdx.x == 0 && threadIdx.x < nbuck)
        cursor[threadIdx.x] = threadIdx.x * PCAP;
}

// ---- k1: partition edges into buckets, LDS-compacted write-out ----
__global__ __launch_bounds__(PT) void k_part(
    const int* __restrict__ ei, int* __restrict__ cursor,
    int* __restrict__ dsts, int n_edges, int nbuck)
{
    __shared__ int lcnt[512];
    __shared__ int loff[512];
    __shared__ int sbase[512];
    __shared__ int sw[8];
    __shared__ int val[PT * PEPT];              // 16 KB compacted edges
    __shared__ unsigned short bid[PT * PEPT];   // 8 KB bucket ids
    int tid = threadIdx.x;
    int lane = tid & 63, wid = tid >> 6;
    lcnt[tid] = 0;
    __syncthreads();

    int e0 = blockIdx.x * (PT * PEPT);
    int bk[PEPT], rk[PEPT], pk[PEPT];
    #pragma unroll
    for (int k = 0; k < PEPT; ++k) {
        int e = e0 + k * PT + tid;
        if (e < n_edges) {
            int src = ei[e];
            int dst = ei[n_edges + e];
            int b = dst >> 8;
            bk[k] = b;
            pk[k] = (src << 8) | (dst & 255);
            rk[k] = atomicAdd(&lcnt[b], 1);
        } else bk[k] = -1;
    }
    __syncthreads();
    // exclusive scan lcnt[0..512) -> loff; reserve global windows -> sbase
    int v = lcnt[tid];
    int s = v;
    #pragma unroll
    for (int off = 1; off < 64; off <<= 1) {
        int u = __shfl_up(s, off);
        if (lane >= off) s += u;
    }
    if (lane == 63) sw[wid] = s;
    sbase[tid] = v ? atomicAdd(&cursor[tid], v) : 0;   // tid<512 within cursor buf
    __syncthreads();
    if (tid == 0) { int a = 0; for (int i = 0; i < 8; ++i) { int t2 = sw[i]; sw[i] = a; a += t2; } }
    __syncthreads();
    loff[tid] = (s - v) + sw[wid];
    __syncthreads();
    // compact into LDS
    #pragma unroll
    for (int k = 0; k < PEPT; ++k)
        if (bk[k] >= 0) {
            int p = loff[bk[k]] + rk[k];
            val[p] = pk[k];
            bid[p] = (unsigned short)bk[k];
        }
    __syncthreads();
    // linear write-out: consecutive threads -> consecutive run elements
    int ntot = loff[511] + lcnt[511];
    for (int i = tid; i < ntot; i += PT) {
        int b = bid[i];
        dsts[sbase[b] + (i - loff[b])] = val[i];
    }
}

// ---- k3: per-bucket counting sort, LDS-compacted -> sequential csr write ----
__global__ __launch_bounds__(ST) void k_bsort(
    const int* __restrict__ dsts, const int* __restrict__ cursor,
    int* __restrict__ csr_src,
    int* __restrict__ row_start, int* __restrict__ row_end, int n_nodes)
{
    __shared__ int cnt[256];
    __shared__ int off[256];
    __shared__ int lval[PCAP];                  // 24 KB compacted srcs
    int b = blockIdx.x;
    int tid = threadIdx.x, lane = tid & 63, wid = tid >> 6;
    int s = cursor[b] - b * PCAP;
    int gin = b * PCAP;
    if (tid < 256) cnt[tid] = 0;
    __syncthreads();

    int dk[SEPT], rk[SEPT], sk[SEPT];
    #pragma unroll
    for (int k = 0; k < SEPT; ++k) {
        int i = k * ST + tid;
        if (i < s) {
            int p = dsts[gin + i];
            int d = p & 255;
            dk[k] = d;
            sk[k] = p >> 8;
            rk[k] = atomicAdd(&cnt[d], 1);
        } else dk[k] = -1;
    }
    __syncthreads();
    if (wid == 0) {
        int c0 = cnt[lane * 4], c1 = cnt[lane * 4 + 1], c2 = cnt[lane * 4 + 2], c3 = cnt[lane * 4 + 3];
        int p1 = c0, p2 = p1 + c1, p3 = p2 + c2, p4 = p3 + c3;
        int ss = p4;
        #pragma unroll
        for (int o = 1; o < 64; o <<= 1) {
            int u = __shfl_up(ss, o);
            if (lane >= o) ss += u;
        }
        int base = ss - p4;
        off[lane * 4] = base; off[lane * 4 + 1] = base + p1;
        off[lane * 4 + 2] = base + p2; off[lane * 4 + 3] = base + p3;
    }
    __syncthreads();
    // compact into LDS by node
    #pragma unroll
    for (int k = 0; k < SEPT; ++k)
        if (dk[k] >= 0) lval[off[dk[k]] + rk[k]] = sk[k];
    __syncthreads();
    // fully sequential csr window write
    int bb = b * PCAP;
    for (int i = tid; i < s; i += ST) csr_src[bb + i] = lval[i];
    int node = b * 256 + tid;
    if (tid < 256 && node < n_nodes) {
        row_start[node] = bb + off[tid];
        row_end[node]   = bb + off[tid] + cnt[tid];
    }
}

// ---- k4: fused gather + MLP, 4 nodes/wave, 16B fp16 loads, 2 edges in flight ----
// (byte-identical to R11-verified: 69us, FETCH 92MB)
__global__ __launch_bounds__(512) void k_gather_mlp(
    const float4* __restrict__ x4,     // [n][16] fp32 (self term)
    const uint2* __restrict__ xh,      // [n][16] fp16x4 (neighbor gather)
    const int* __restrict__ row_start,
    const int* __restrict__ row_end,
    const int* __restrict__ csr_src,
    const float* __restrict__ eps_p,
    const float* __restrict__ W1,
    const float* __restrict__ b1,
    const float* __restrict__ W2,
    const float* __restrict__ b2,
    float* __restrict__ out,
    int n_nodes)
{
    __shared__ float sW1[NFEAT * NHID];   // [k][j] 16 KB
    __shared__ float sW2[NHID * 17];      // [j][c] padded
    __shared__ float sb1[NHID];
    __shared__ float sb2[NCLASS];
    __shared__ float sh0[32][68];         // 32 nodes/block, padded rows
    __shared__ float sh1[32][68];
    __shared__ int   sIdx[8][64];

    int tid = threadIdx.x;
    for (int i = tid; i < NFEAT * NHID; i += 512) sW1[i] = W1[i];
    for (int i = tid; i < NHID * NCLASS; i += 512) sW2[(i >> 4) * 17 + (i & 15)] = W2[i];
    if (tid < NHID) sb1[tid] = b1[tid];
    if (tid < NCLASS) sb2[tid] = b2[tid];
    __syncthreads();

    float eps1 = 1.0f + eps_p[0];
    int wave = tid >> 6;
    int lane = tid & 63;
    int q = lane >> 4;        // node sub-index 0..3
    int f = lane & 15;        // staging slot 0..15 / layer2 class slot
    int s8 = (lane >> 3) & 1; // edge parity within group
    int f8 = lane & 7;        // feature octet 0..7 (16B of fp16)
    int nloc = wave * 4 + q;  // local node row

    for (int nb0 = blockIdx.x * 32; nb0 < n_nodes; nb0 += gridDim.x * 32) {
        int myNode = nb0 + nloc;
        bool valid = myNode < n_nodes;
        int s = 0, e = 0;
        if (valid) { s = row_start[myNode]; e = row_end[myNode]; }
        int dmax = e - s;
        dmax = max(dmax, __shfl_xor(dmax, 16));
        dmax = max(dmax, __shfl_xor(dmax, 32));

        // accA = features f8*8..+3, accB = f8*8+4..+7 (partial over edge parity s8)
        float4 accA = make_float4(0.f, 0.f, 0.f, 0.f);
        float4 accB = make_float4(0.f, 0.f, 0.f, 0.f);
        for (int base = 0; base < dmax; base += 16) {
            int p = s + base + f;                       // lane stages slot q*16+f
            sIdx[wave][lane] = (p < e) ? csr_src[p] : -1;
            // wave-lockstep LDS write->read, no barrier
            #pragma unroll
            for (int t = 0; t < 8; ++t) {
                int idx = sIdx[wave][q * 16 + t * 2 + s8];
                if (idx >= 0) {
                    const uint4* rp = (const uint4*)(xh + (size_t)idx * 16);
                    uint4 u = rp[f8];                   // 16B = 8 fp16 features
                    __half2 h0 = *reinterpret_cast<__half2*>(&u.x);
                    __half2 h1 = *reinterpret_cast<__half2*>(&u.y);
                    __half2 h2 = *reinterpret_cast<__half2*>(&u.z);
                    __half2 h3 = *reinterpret_cast<__half2*>(&u.w);
                    float2 g0 = __half22float2(h0);
                    float2 g1 = __half22float2(h1);
                    float2 g2 = __half22float2(h2);
                    float2 g3 = __half22float2(h3);
                    accA.x += g0.x; accA.y += g0.y; accA.z += g1.x; accA.w += g1.y;
                    accB.x += g2.x; accB.y += g2.y; accB.z += g3.x; accB.w += g3.y;
                }
            }
        }
        // combine the two edge-parity partials (lane ^ 8 within 16-lane group)
        accA.x += __shfl_xor(accA.x, 8); accA.y += __shfl_xor(accA.y, 8);
        accA.z += __shfl_xor(accA.z, 8); accA.w += __shfl_xor(accA.w, 8);
        accB.x += __shfl_xor(accB.x, 8); accB.y += __shfl_xor(accB.y, 8);
        accB.z += __shfl_xor(accB.z, 8); accB.w += __shfl_xor(accB.w, 8);
        if (s8 == 0) {
            if (valid) {
                float4 xa = x4[(size_t)myNode * 16 + f8 * 2];
                float4 xb = x4[(size_t)myNode * 16 + f8 * 2 + 1];
                accA.x += eps1 * xa.x; accA.y += eps1 * xa.y;
                accA.z += eps1 * xa.z; accA.w += eps1 * xa.w;
                accB.x += eps1 * xb.x; accB.y += eps1 * xb.y;
                accB.z += eps1 * xb.z; accB.w += eps1 * xb.w;
            }
            *(float4*)&sh0[nloc][f8 * 8] = accA;
            *(float4*)&sh0[nloc][f8 * 8 + 4] = accB;
        }

        // layer1: lane j computes h1[j] for the wave's 4 nodes
        int r = wave * 4;
        float a0 = sb1[lane], a1 = a0, a2 = a0, a3 = a0;
        #pragma unroll
        for (int kk = 0; kk < 16; ++kk) {
            float4 h0 = *(const float4*)&sh0[r + 0][kk * 4];   // broadcast reads
            float4 h1v = *(const float4*)&sh0[r + 1][kk * 4];
            float4 h2 = *(const float4*)&sh0[r + 2][kk * 4];
            float4 h3 = *(const float4*)&sh0[r + 3][kk * 4];
            #pragma unroll
            for (int i = 0; i < 4; ++i) {
                float w = sW1[(kk * 4 + i) * NHID + lane];
                a0 += ((const float*)&h0)[i] * w;
                a1 += ((const float*)&h1v)[i] * w;
                a2 += ((const float*)&h2)[i] * w;
                a3 += ((const float*)&h3)[i] * w;
            }
        }
        sh1[r + 0][lane] = fmaxf(a0, 0.f);
        sh1[r + 1][lane] = fmaxf(a1, 0.f);
        sh1[r + 2][lane] = fmaxf(a2, 0.f);
        sh1[r + 3][lane] = fmaxf(a3, 0.f);

        // layer2: lane (q,f) -> out[myNode][f]
        float o = sb2[f];
        #pragma unroll
        for (int jj = 0; jj < 16; ++jj) {
            float4 hv = *(const float4*)&sh1[nloc][jj * 4];
            o += hv.x * sW2[(jj * 4 + 0) * 17 + f];
            o += hv.y * sW2[(jj * 4 + 1) * 17 + f];
            o += hv.z * sW2[(jj * 4 + 2) * 17 + f];
            o += hv.w * sW2[(jj * 4 + 3) * 17 + f];
        }
        if (valid) out[(size_t)myNode * NCLASS + f] = o;
    }
}

extern "C" void kernel_launch(void* const* d_in, const int* in_sizes, int n_in,
                              void* d_out, int out_size, void* d_ws, size_t ws_size,
                              hipStream_t stream) {
    const float* x   = (const float*)d_in[0];
    const int*   ei  = (const int*)d_in[1];
    const float* eps = (const float*)d_in[2];
    const float* W1  = (const float*)d_in[3];
    const float* b1  = (const float*)d_in[4];
    const float* W2  = (const float*)d_in[5];
    const float* b2  = (const float*)d_in[6];
    float* out = (float*)d_out;

    int n_nodes = in_sizes[0] / NFEAT;            // 100000
    int n_edges = in_sizes[1] / 2;                // 1600000
    int nbuck = (n_nodes + 255) / 256;            // 391

    char* ws = (char*)d_ws;
    int* cursor    = (int*)ws;                               // 4KB (512 ints ok)
    int* dsts      = (int*)(ws + 4096);                      // nbuck*PCAP*4
    size_t o_rs    = 4096 + (size_t)nbuck * PCAP * 4;
    int* row_start = (int*)(ws + o_rs);                      // 400128
    int* row_end   = (int*)(ws + o_rs + 400128);             // 400128
    int* csr_src   = (int*)(ws + o_rs + 800256);             // nbuck*PCAP*4
    size_t o_xh    = o_rs + 800256 + (size_t)nbuck * PCAP * 4;
    o_xh = (o_xh + 15) & ~(size_t)15;
    uint2* xh      = (uint2*)(ws + o_xh);                    // [n][16] fp16x4

    int n4 = n_nodes * 16;
    k_cvt<<<(n4 + 511) / 512, 512, 0, stream>>>((const float4*)x, xh, cursor, n4, nbuck);
    k_part<<<(n_edges + PT * PEPT - 1) / (PT * PEPT), PT, 0, stream>>>(
        ei, cursor, dsts, n_edges, nbuck);
    k_bsort<<<nbuck, ST, 0, stream>>>(dsts, cursor, csr_src, row_start, row_end, n_nodes);
    int ntile = (n_nodes + 31) / 32;
    int ngrid = ntile < 1024 ? ntile : 1024;      // grid-stride ~3 tiles/block
    k_gather_mlp<<<ngrid, 512, 0, stream>>>(
        (const float4*)x, xh, row_start, row_end, csr_src, eps, W1, b1, W2, b2, out, n_nodes);
}